// Round 7
// baseline (194.076 us; speedup 1.0000x reference)
//
#include <hip/hip_runtime.h>

#define NB 8732
#define NC 21
#define BATCH 128
#define BXS 7                 // blocks per row
#define WPR 28                // waves per row (BXS*4)
#define STRIDE (WPR * 64)     // 1792 boxes between a wave's consecutive tiles
#define WS_ROW (BATCH * BXS * 4)

__device__ inline float wred_f(float v) {
#pragma unroll
    for (int o = 32; o > 0; o >>= 1) v += __shfl_down(v, o, 64);
    return v;
}

// Persistent pipelined wave: ~5 tiles/wave, register double-buffer.
// While tile t is transposed through wave-private LDS + softmaxed, tile t+1's
// 21 coalesced conf loads + loc/label loads are in flight. No __syncthreads
// in the main loop, no atomics anywhere.
__global__ void __launch_bounds__(256, 4)
kA(const float* __restrict__ locp, const float* __restrict__ loct,
   const float* __restrict__ conf, const int* __restrict__ lab,
   float* __restrict__ ws) {
    __shared__ float xb[4][1344];
    const int r = blockIdx.y;
    const int w = threadIdx.x >> 6;
    const int ln = threadIdx.x & 63;
    float* X = xb[w];
    const int wid = blockIdx.x * 4 + w;          // 0..27, first tile always valid
    const size_t rowbase = (size_t)r * NB;
    const float* __restrict__ crow = conf + rowbase * NC;

    float ceS = 0.f, pceS = 0.f, llS = 0.f, npS = 0.f;

    float v[2][21];
    int lv[2];
    float4 lp[2], lt[2];

#define LOADT(B, BOX0, CNT)                                                   \
    {                                                                         \
        const float* __restrict__ src = crow + (size_t)(BOX0) * NC;           \
        if ((CNT) == 64) {                                                    \
            _Pragma("unroll") for (int j = 0; j < 21; j++)                    \
                v[B][j] = src[64 * j + ln];                                   \
        } else {                                                              \
            const int nflat = (CNT) * NC;                                     \
            _Pragma("unroll") for (int j = 0; j < 21; j++) {                  \
                const int idx = 64 * j + ln;                                  \
                v[B][j] = (idx < nflat) ? src[idx] : 0.f;                     \
            }                                                                 \
        }                                                                     \
        lv[B] = 0;                                                            \
        if (ln < (CNT)) {                                                     \
            const size_t box = rowbase + (BOX0) + ln;                         \
            lv[B] = lab[box];                                                 \
            lp[B] = *(const float4*)(locp + box * 4);                         \
            lt[B] = *(const float4*)(loct + box * 4);                         \
        }                                                                     \
    }

#define WLDS(B, CNT)                                                          \
    {                                                                         \
        if ((CNT) == 64) {                                                    \
            _Pragma("unroll") for (int j = 0; j < 21; j++)                    \
                X[64 * j + ln] = v[B][j];                                     \
        } else {                                                              \
            const int nflat = (CNT) * NC;                                     \
            _Pragma("unroll") for (int j = 0; j < 21; j++) {                  \
                const int idx = 64 * j + ln;                                  \
                if (idx < nflat) X[idx] = v[B][j];                            \
            }                                                                 \
        }                                                                     \
    }

#define CONSUME(B, CNT)                                                       \
    {                                                                         \
        asm volatile("s_waitcnt lgkmcnt(0)" ::: "memory");                    \
        if (ln < (CNT)) {                                                     \
            float c[21];                                                      \
            const float* bp = &X[21 * ln];                                    \
            _Pragma("unroll") for (int j = 0; j < 21; j++) c[j] = bp[j];      \
            float m = c[0];                                                   \
            _Pragma("unroll") for (int j = 1; j < 21; j++) m = fmaxf(m, c[j]);\
            float s = 0.f;                                                    \
            _Pragma("unroll") for (int j = 0; j < 21; j++)                    \
                s += __expf(c[j] - m);                                        \
            const int l = lv[B];                                              \
            float gold = c[0];                                                \
            _Pragma("unroll") for (int j = 1; j < 21; j++)                    \
                gold = (j == l) ? c[j] : gold;                                \
            const float ce = m + __logf(s) - gold;                            \
            ceS += ce;                                                        \
            if (l > 0) {                                                      \
                npS += 1.f; pceS += ce;                                       \
                const float4 P = lp[B], T = lt[B];                            \
                float d, ad;                                                  \
                d = P.x - T.x; ad = fabsf(d); llS += (ad < 1.f) ? 0.5f * d * d : ad - 0.5f; \
                d = P.y - T.y; ad = fabsf(d); llS += (ad < 1.f) ? 0.5f * d * d : ad - 0.5f; \
                d = P.z - T.z; ad = fabsf(d); llS += (ad < 1.f) ? 0.5f * d * d : ad - 0.5f; \
                d = P.w - T.w; ad = fabsf(d); llS += (ad < 1.f) ? 0.5f * d * d : ad - 0.5f; \
            }                                                                 \
        }                                                                     \
    }

    int b0 = wid * 64;                        // always < NB (wid<=27 -> 1728)
    int c0 = min(64, NB - b0);
    LOADT(0, b0, c0)
    int b1 = b0 + STRIDE;
    bool have1 = (b1 < NB);
    int c1 = have1 ? min(64, NB - b1) : 0;

    for (;;) {
        // consume buffer 0 (tile b0), prefetch into buffer 1
        WLDS(0, c0)
        if (have1) LOADT(1, b1, c1)
        CONSUME(0, c0)
        if (!have1) break;
        // consume buffer 1, prefetch into buffer 0
        b0 = b1 + STRIDE;
        const bool have0 = (b0 < NB);
        c0 = have0 ? min(64, NB - b0) : 0;
        WLDS(1, c1)
        if (have0) LOADT(0, b0, c0)
        CONSUME(1, c1)
        if (!have0) break;
        b1 = b0 + STRIDE;
        have1 = (b1 < NB);
        c1 = have1 ? min(64, NB - b1) : 0;
    }

    // block reduction -> private slot (plain stores, no atomics, no zero-init)
    __shared__ float sr[4][4];
    float r0 = wred_f(ceS), r1 = wred_f(pceS), r2 = wred_f(llS), r3 = wred_f(npS);
    if (ln == 0) { sr[0][w] = r0; sr[1][w] = r1; sr[2][w] = r2; sr[3][w] = r3; }
    __syncthreads();
    if (threadIdx.x == 0) {
        float A = 0, B = 0, C = 0, D = 0;
#pragma unroll
        for (int k = 0; k < 4; k++) { A += sr[0][k]; B += sr[1][k]; C += sr[2][k]; D += sr[3][k]; }
        float* slot = ws + ((size_t)r * BXS + blockIdx.x) * 4;
        slot[0] = A; slot[1] = B; slot[2] = C; slot[3] = D;
    }
}

__device__ inline float ce_for_box0(const float* __restrict__ cp) {
    float c[NC];
#pragma unroll
    for (int j = 0; j < NC; j++) c[j] = cp[j];
    float m = c[0];
#pragma unroll
    for (int j = 1; j < NC; j++) m = fmaxf(m, c[j]);
    float s = 0.f;
#pragma unroll
    for (int j = 0; j < NC; j++) s += __expf(c[j] - m);
    return m + __logf(s) - c[0];
}

// Block r: reduce BXS partial slots -> row sums; mining decision.
// Hot path (K >= #neg, always true on this data): conf_row = row_ce, no sort.
// Cold path: exact top-K radix select (tie values identical -> sum exact).
__global__ void __launch_bounds__(256)
kB(const float* __restrict__ conf, const int* __restrict__ lab,
   float* __restrict__ ws) {
    const int r = blockIdx.x;
    __shared__ float srow[4];
    if (threadIdx.x < 64) {
        float a = 0, b = 0, c = 0, d = 0;
        if (threadIdx.x < BXS) {
            const float4 p = *(const float4*)(ws + ((size_t)r * BXS + threadIdx.x) * 4);
            a = p.x; b = p.y; c = p.z; d = p.w;
        }
        a = wred_f(a); b = wred_f(b); c = wred_f(c); d = wred_f(d);
        if (threadIdx.x == 0) { srow[0] = a; srow[1] = b; srow[2] = c; srow[3] = d; }
    }
    __syncthreads();
    const float row_ce = srow[0], row_pce = srow[1], row_ll = srow[2];
    const int np = (int)srow[3];
    const int K = min(3 * np, NB - 1);
    const int nneg = NB - np;

    float rowval;
    if (K >= nneg) {
        rowval = row_ce;
    } else if (K <= 0) {
        rowval = row_pce;
    } else {
        __shared__ unsigned key[NB];
        __shared__ unsigned hist[256];
        __shared__ unsigned sb[2];
        for (int i = threadIdx.x; i < NB; i += 256) {
            const size_t box = (size_t)r * NB + i;
            unsigned k = 0u;
            if (lab[box] == 0) {
                float ce = ce_for_box0(conf + box * (size_t)NC);
                k = __float_as_uint(fmaxf(ce, 0.f));
            }
            key[i] = k;
        }
        __syncthreads();
        unsigned prefix = 0;
        int Kr = K;
        for (int round = 3; round >= 0; --round) {
            const int sh = round * 8;
            const unsigned pmask = (round == 3) ? 0u : (0xFFFFFFFFu << (8 * (round + 1)));
            for (int b = threadIdx.x; b < 256; b += 256) hist[b] = 0;
            __syncthreads();
            for (int i = threadIdx.x; i < NB; i += 256) {
                const unsigned k = key[i];
                if ((k & pmask) == prefix) atomicAdd(&hist[(k >> sh) & 255u], 1u);
            }
            __syncthreads();
            if (threadIdx.x == 0) {
                unsigned cum = 0; int b = 255;
                for (; b > 0; --b) {
                    const unsigned h = hist[b];
                    if (cum + h >= (unsigned)Kr) break;
                    cum += h;
                }
                sb[0] = cum; sb[1] = (unsigned)b;
            }
            __syncthreads();
            Kr -= (int)sb[0];
            prefix |= (sb[1] << sh);
            __syncthreads();
        }
        float local = 0.f;
        for (int i = threadIdx.x; i < NB; i += 256) {
            const unsigned k = key[i];
            if (k > prefix) local += __uint_as_float(k);
        }
        __shared__ float sred[4];
        float vv = wred_f(local);
        const int ww = threadIdx.x >> 6, lnn = threadIdx.x & 63;
        if (lnn == 0) sred[ww] = vv;
        __syncthreads();
        rowval = row_pce + sred[0] + sred[1] + sred[2] + sred[3]
               + (float)Kr * __uint_as_float(prefix);
    }

    if (threadIdx.x == 0) {
        float* o = ws + WS_ROW + r * 4;
        o[0] = rowval; o[1] = row_ll; o[2] = srow[3];
    }
}

// Single block: reduce the 128 per-row results -> final scalar.
__global__ void __launch_bounds__(256)
kC(const float* __restrict__ ws, float* __restrict__ out) {
    float cf = 0.f, lc = 0.f, nm = 0.f;
    if (threadIdx.x < BATCH) {
        const float* o = ws + WS_ROW + threadIdx.x * 4;
        cf = o[0]; lc = o[1]; nm = o[2];
    }
    __shared__ float sf[4], sl[4], sn[4];
    float vc = wred_f(cf), vl = wred_f(lc), vn = wred_f(nm);
    const int w = threadIdx.x >> 6, ln = threadIdx.x & 63;
    if (ln == 0) { sf[w] = vc; sl[w] = vl; sn[w] = vn; }
    __syncthreads();
    if (threadIdx.x == 0) {
        const float CF = sf[0] + sf[1] + sf[2] + sf[3];
        const float LC = sl[0] + sl[1] + sl[2] + sl[3];
        const float NM = sn[0] + sn[1] + sn[2] + sn[3];
        out[0] = (LC + CF) / fmaxf(NM, 1.f);
    }
}

extern "C" void kernel_launch(void* const* d_in, const int* in_sizes, int n_in,
                              void* d_out, int out_size, void* d_ws, size_t ws_size,
                              hipStream_t stream) {
    const float* locp = (const float*)d_in[0];
    const float* loct = (const float*)d_in[1];
    const float* conf = (const float*)d_in[2];
    const int* lab = (const int*)d_in[3];
    float* out = (float*)d_out;
    float* ws = (float*)d_ws;

    hipLaunchKernelGGL(kA, dim3(BXS, BATCH), dim3(256), 0, stream,
                       locp, loct, conf, lab, ws);
    hipLaunchKernelGGL(kB, dim3(BATCH), dim3(256), 0, stream, conf, lab, ws);
    hipLaunchKernelGGL(kC, dim3(1), dim3(256), 0, stream, ws, out);
}

// Round 8
// 179.309 us; speedup vs baseline: 1.0824x; 1.0824x over previous
//
#include <hip/hip_runtime.h>

#define NB 8732
#define NC 21
#define BATCH 128
#define WPR 20                  // waves (=blocks of 64) per row
#define NFULL 136               // full 64-box tiles per row (tile 136 is partial: 28 boxes)
#define WS_ROW (BATCH * WPR * 4)

__device__ inline float wred_f(float v) {
#pragma unroll
    for (int o = 32; o > 0; o >>= 1) v += __shfl_down(v, o, 64);
    return v;
}

__device__ __forceinline__ void gl_lds16(const void* g, void* l) {
    __builtin_amdgcn_global_load_lds((const __attribute__((address_space(1))) void*)g,
                                     (__attribute__((address_space(3))) void*)l, 16, 0, 0);
}
__device__ __forceinline__ void gl_lds4(const void* g, void* l) {
    __builtin_amdgcn_global_load_lds((const __attribute__((address_space(1))) void*)g,
                                     (__attribute__((address_space(3))) void*)l, 4, 0, 0);
}

__device__ __forceinline__ void box_accum(const float c[21], int l,
                                          float4 lp, float4 lt,
                                          float& ceS, float& pceS, float& llS, float& npS) {
    float m = c[0];
#pragma unroll
    for (int j = 1; j < 21; j++) m = fmaxf(m, c[j]);
    float s = 0.f;
#pragma unroll
    for (int j = 0; j < 21; j++) s += __expf(c[j] - m);
    float gold = c[0];
#pragma unroll
    for (int j = 1; j < 21; j++) gold = (j == l) ? c[j] : gold;
    const float ce = m + __logf(s) - gold;
    ceS += ce;
    if (l > 0) {
        npS += 1.f; pceS += ce;
        float d, ad;
        d = lp.x - lt.x; ad = fabsf(d); llS += (ad < 1.f) ? 0.5f * d * d : ad - 0.5f;
        d = lp.y - lt.y; ad = fabsf(d); llS += (ad < 1.f) ? 0.5f * d * d : ad - 0.5f;
        d = lp.z - lt.z; ad = fabsf(d); llS += (ad < 1.f) ? 0.5f * d * d : ad - 0.5f;
        d = lp.w - lt.w; ad = fabsf(d); llS += (ad < 1.f) ? 0.5f * d * d : ad - 0.5f;
    }
}

// One wave per block. Depth-1 software pipeline: tile t+1's 9 global_load_lds
// (zero staging VGPRs, 1KB-coalesced) fly during tile t's consume.
// s_waitcnt vmcnt(9) = "tile t fully landed" (all loop VMEM events are ours,
// in-order retirement). LDS buffer layout (dwords):
//   [0..1343]=conf  [1344..1599]=locp  [1600..1855]=loct  [1856..1919]=lab
__global__ void __launch_bounds__(64)
kA(const float* __restrict__ locp, const float* __restrict__ loct,
   const float* __restrict__ conf, const int* __restrict__ lab,
   float* __restrict__ ws) {
    __shared__ float buf[2][1920];
    const int r = blockIdx.y;
    const int wid = blockIdx.x;                  // 0..WPR-1
    const int ln = threadIdx.x;                  // 0..63
    const size_t rowbase = (size_t)r * NB;

    float ceS = 0.f, pceS = 0.f, llS = 0.f, npS = 0.f;

#define ISSUE(B, BOX0)                                                        \
    {                                                                         \
        const char* gc = (const char*)(conf + (rowbase + (size_t)(BOX0)) * NC); \
        _Pragma("unroll") for (int k = 0; k < 5; k++)                         \
            gl_lds16(gc + k * 1024 + ln * 16, &buf[B][k * 256]);              \
        if (ln < 16) gl_lds16(gc + 5120 + ln * 16, &buf[B][1280]);            \
        gl_lds16((const char*)(locp + (rowbase + (BOX0)) * 4) + ln * 16,      \
                 &buf[B][1344]);                                              \
        gl_lds16((const char*)(loct + (rowbase + (BOX0)) * 4) + ln * 16,      \
                 &buf[B][1600]);                                              \
        gl_lds4((const char*)(lab + rowbase + (BOX0)) + ln * 4,               \
                &buf[B][1856]);                                               \
    }

#define CONSUME(B)                                                            \
    {                                                                         \
        float c[21];                                                          \
        _Pragma("unroll") for (int j = 0; j < 21; j++)                        \
            c[j] = buf[B][21 * ln + j];                                       \
        const int l = ((const int*)(&buf[B][1856]))[ln];                      \
        const float4 lp = ((const float4*)(&buf[B][1344]))[ln];               \
        const float4 lt = ((const float4*)(&buf[B][1600]))[ln];               \
        box_accum(c, l, lp, lt, ceS, pceS, llS, npS);                         \
    }

    // full tiles for this wave: t = wid + WPR*i, t <= NFULL-1
    const int ntiles = (NFULL - 1 - wid) / WPR + 1;

    ISSUE(0, wid * 64)
    for (int i = 0; i < ntiles; i++) {
        const bool more = (i + 1) < ntiles;
        if (more) {
            const int nbox = (wid + (i + 1) * WPR) * 64;
            if ((i & 1) == 0) ISSUE(1, nbox) else ISSUE(0, nbox)
            asm volatile("s_waitcnt vmcnt(9)" ::: "memory");
        } else {
            asm volatile("s_waitcnt vmcnt(0)" ::: "memory");
        }
        if ((i & 1) == 0) CONSUME(0) else CONSUME(1)
    }

    // partial tile 136 (28 boxes), one wave per row, plain loads (tiny)
    if (wid == (NFULL % WPR)) {
        if (ln < NB - NFULL * 64) {
            const size_t box = rowbase + NFULL * 64 + ln;
            const float* cp = conf + box * (size_t)NC;
            float c[21];
#pragma unroll
            for (int j = 0; j < 21; j++) c[j] = cp[j];
            const int l = lab[box];
            const float4 lp = *(const float4*)(locp + box * 4);
            const float4 lt = *(const float4*)(loct + box * 4);
            box_accum(c, l, lp, lt, ceS, pceS, llS, npS);
        }
    }

    // wave == block: shuffle-reduce, lane 0 stores private slot (no atomics)
    float A = wred_f(ceS), Bv = wred_f(pceS), C = wred_f(llS), D = wred_f(npS);
    if (ln == 0) {
        float4* slot = (float4*)(ws + ((size_t)r * WPR + wid) * 4);
        *slot = make_float4(A, Bv, C, D);
    }
}

__device__ inline float ce_for_box0(const float* __restrict__ cp) {
    float c[NC];
#pragma unroll
    for (int j = 0; j < NC; j++) c[j] = cp[j];
    float m = c[0];
#pragma unroll
    for (int j = 1; j < NC; j++) m = fmaxf(m, c[j]);
    float s = 0.f;
#pragma unroll
    for (int j = 0; j < NC; j++) s += __expf(c[j] - m);
    return m + __logf(s) - c[0];
}

// Block r: reduce WPR partial slots -> row sums; mining decision.
// Hot path (K >= #neg, always true on this data): conf_row = row_ce, no sort.
// Cold path: exact top-K radix select (tie values identical -> sum exact).
__global__ void __launch_bounds__(256)
kB(const float* __restrict__ conf, const int* __restrict__ lab,
   float* __restrict__ ws) {
    const int r = blockIdx.x;
    __shared__ float srow[4];
    if (threadIdx.x < 64) {
        float a = 0, b = 0, c = 0, d = 0;
        if (threadIdx.x < WPR) {
            const float4 p = *(const float4*)(ws + ((size_t)r * WPR + threadIdx.x) * 4);
            a = p.x; b = p.y; c = p.z; d = p.w;
        }
        a = wred_f(a); b = wred_f(b); c = wred_f(c); d = wred_f(d);
        if (threadIdx.x == 0) { srow[0] = a; srow[1] = b; srow[2] = c; srow[3] = d; }
    }
    __syncthreads();
    const float row_ce = srow[0], row_pce = srow[1], row_ll = srow[2];
    const int np = (int)srow[3];
    const int K = min(3 * np, NB - 1);
    const int nneg = NB - np;

    float rowval;
    if (K >= nneg) {
        rowval = row_ce;
    } else if (K <= 0) {
        rowval = row_pce;
    } else {
        __shared__ unsigned key[NB];
        __shared__ unsigned hist[256];
        __shared__ unsigned sb[2];
        for (int i = threadIdx.x; i < NB; i += 256) {
            const size_t box = (size_t)r * NB + i;
            unsigned k = 0u;
            if (lab[box] == 0) {
                float ce = ce_for_box0(conf + box * (size_t)NC);
                k = __float_as_uint(fmaxf(ce, 0.f));
            }
            key[i] = k;
        }
        __syncthreads();
        unsigned prefix = 0;
        int Kr = K;
        for (int round = 3; round >= 0; --round) {
            const int sh = round * 8;
            const unsigned pmask = (round == 3) ? 0u : (0xFFFFFFFFu << (8 * (round + 1)));
            for (int b = threadIdx.x; b < 256; b += 256) hist[b] = 0;
            __syncthreads();
            for (int i = threadIdx.x; i < NB; i += 256) {
                const unsigned k = key[i];
                if ((k & pmask) == prefix) atomicAdd(&hist[(k >> sh) & 255u], 1u);
            }
            __syncthreads();
            if (threadIdx.x == 0) {
                unsigned cum = 0; int b = 255;
                for (; b > 0; --b) {
                    const unsigned h = hist[b];
                    if (cum + h >= (unsigned)Kr) break;
                    cum += h;
                }
                sb[0] = cum; sb[1] = (unsigned)b;
            }
            __syncthreads();
            Kr -= (int)sb[0];
            prefix |= (sb[1] << sh);
            __syncthreads();
        }
        float local = 0.f;
        for (int i = threadIdx.x; i < NB; i += 256) {
            const unsigned k = key[i];
            if (k > prefix) local += __uint_as_float(k);
        }
        __shared__ float sred[4];
        float vv = wred_f(local);
        const int ww = threadIdx.x >> 6, lnn = threadIdx.x & 63;
        if (lnn == 0) sred[ww] = vv;
        __syncthreads();
        rowval = row_pce + sred[0] + sred[1] + sred[2] + sred[3]
               + (float)Kr * __uint_as_float(prefix);
    }

    if (threadIdx.x == 0) {
        float* o = ws + WS_ROW + r * 4;
        o[0] = rowval; o[1] = row_ll; o[2] = srow[3];
    }
}

// Single block: reduce the 128 per-row results -> final scalar.
__global__ void __launch_bounds__(256)
kC(const float* __restrict__ ws, float* __restrict__ out) {
    float cf = 0.f, lc = 0.f, nm = 0.f;
    if (threadIdx.x < BATCH) {
        const float* o = ws + WS_ROW + threadIdx.x * 4;
        cf = o[0]; lc = o[1]; nm = o[2];
    }
    __shared__ float sf[4], sl[4], sn[4];
    float vc = wred_f(cf), vl = wred_f(lc), vn = wred_f(nm);
    const int w = threadIdx.x >> 6, ln = threadIdx.x & 63;
    if (ln == 0) { sf[w] = vc; sl[w] = vl; sn[w] = vn; }
    __syncthreads();
    if (threadIdx.x == 0) {
        const float CF = sf[0] + sf[1] + sf[2] + sf[3];
        const float LC = sl[0] + sl[1] + sl[2] + sl[3];
        const float NM = sn[0] + sn[1] + sn[2] + sn[3];
        out[0] = (LC + CF) / fmaxf(NM, 1.f);
    }
}

extern "C" void kernel_launch(void* const* d_in, const int* in_sizes, int n_in,
                              void* d_out, int out_size, void* d_ws, size_t ws_size,
                              hipStream_t stream) {
    const float* locp = (const float*)d_in[0];
    const float* loct = (const float*)d_in[1];
    const float* conf = (const float*)d_in[2];
    const int* lab = (const int*)d_in[3];
    float* out = (float*)d_out;
    float* ws = (float*)d_ws;

    hipLaunchKernelGGL(kA, dim3(WPR, BATCH), dim3(64), 0, stream,
                       locp, loct, conf, lab, ws);
    hipLaunchKernelGGL(kB, dim3(BATCH), dim3(256), 0, stream, conf, lab, ws);
    hipLaunchKernelGGL(kC, dim3(1), dim3(256), 0, stream, ws, out);
}

// Round 9
// 164.785 us; speedup vs baseline: 1.1778x; 1.0881x over previous
//
#include <hip/hip_runtime.h>

#define NB 8732
#define NC 21
#define BATCH 128
#define BX 35   // ceil(8732/256)

// ws layout (dwords), ALL slots written before read -> no zero-init, no memset:
//   [ (r*35+bx)*4 + {0,1,2,3} ] = block partials {ce, pce, loc, np(float)}
//   [ WS_ROW + r*4 + {0,1,2} ]  = per-row {conf_rowval, loc_row, np_row}
#define WS_ROW (BATCH * BX * 4)

typedef float v4f __attribute__((ext_vector_type(4)));

__device__ inline float wred_f(float v) {
#pragma unroll
    for (int o = 32; o > 0; o >>= 1) v += __shfl_down(v, o, 64);
    return v;
}

// r6 wave-transpose body + NONTEMPORAL global reads (MUBUF nt: L1 no-allocate
// streaming). Theory: per-CU read BW is capped ~4.4 B/cyc by L1 line-fill
// tracking; NT streaming is the only untried path around it.
__global__ void __launch_bounds__(256)
kA(const float* __restrict__ locp, const float* __restrict__ loct,
   const float* __restrict__ conf, const int* __restrict__ lab,
   float* __restrict__ ws) {
    __shared__ float xb[4][1344];
    const int r = blockIdx.y;
    const int w = threadIdx.x >> 6;
    const int ln = threadIdx.x & 63;
    const int box0 = blockIdx.x * 256 + w * 64;

    float ceS = 0.f, pceS = 0.f, llS = 0.f, npS = 0.f;

    if (box0 < NB) {
        const int cnt = min(64, NB - box0);
        const size_t rowbase = (size_t)r * NB;
        const float* __restrict__ src = conf + (rowbase + box0) * (size_t)NC;

        // side loads issued early (NT), in flight during the transpose
        int l = 0;
        v4f lp = {0.f, 0.f, 0.f, 0.f}, lt = {0.f, 0.f, 0.f, 0.f};
        if (ln < cnt) {
            const size_t box = rowbase + box0 + ln;
            l = __builtin_nontemporal_load(lab + box);
            lp = __builtin_nontemporal_load((const v4f*)(locp + box * 4));
            lt = __builtin_nontemporal_load((const v4f*)(loct + box * 4));
        }

        if (cnt == 64) {
            float v[21];
#pragma unroll
            for (int j = 0; j < 21; j++) v[j] = __builtin_nontemporal_load(src + 64 * j + ln);
#pragma unroll
            for (int j = 0; j < 21; j++) xb[w][64 * j + ln] = v[j];
        } else {
            const int nflat = cnt * NC;
#pragma unroll
            for (int j = 0; j < 21; j++) {
                const int idx = 64 * j + ln;
                if (idx < nflat) xb[w][idx] = __builtin_nontemporal_load(src + idx);
            }
        }
        // wave-local cross-lane LDS dependency: drain DS queue, no barrier
        asm volatile("s_waitcnt lgkmcnt(0)" ::: "memory");

        if (ln < cnt) {
            float c[21];
            const float* bp = &xb[w][21 * ln];
#pragma unroll
            for (int j = 0; j < 21; j++) c[j] = bp[j];
            float m = c[0];
#pragma unroll
            for (int j = 1; j < 21; j++) m = fmaxf(m, c[j]);
            float s = 0.f;
#pragma unroll
            for (int j = 0; j < 21; j++) s += __expf(c[j] - m);
            float gold = c[0];
#pragma unroll
            for (int j = 1; j < 21; j++) gold = (j == l) ? c[j] : gold;
            const float ce = m + __logf(s) - gold;
            ceS = ce;
            if (l > 0) {
                npS = 1.f;
                pceS = ce;
                float d, ad;
                d = lp.x - lt.x; ad = fabsf(d); llS += (ad < 1.f) ? 0.5f * d * d : ad - 0.5f;
                d = lp.y - lt.y; ad = fabsf(d); llS += (ad < 1.f) ? 0.5f * d * d : ad - 0.5f;
                d = lp.z - lt.z; ad = fabsf(d); llS += (ad < 1.f) ? 0.5f * d * d : ad - 0.5f;
                d = lp.w - lt.w; ad = fabsf(d); llS += (ad < 1.f) ? 0.5f * d * d : ad - 0.5f;
            }
        }
    }

    __shared__ float sr[4][4];
    float v0 = wred_f(ceS), v1 = wred_f(pceS), v2 = wred_f(llS), v3 = wred_f(npS);
    if (ln == 0) { sr[0][w] = v0; sr[1][w] = v1; sr[2][w] = v2; sr[3][w] = v3; }
    __syncthreads();
    if (threadIdx.x == 0) {
        float A = 0, B = 0, C = 0, D = 0;
#pragma unroll
        for (int k = 0; k < 4; k++) { A += sr[0][k]; B += sr[1][k]; C += sr[2][k]; D += sr[3][k]; }
        float* slot = ws + ((size_t)r * BX + blockIdx.x) * 4;
        slot[0] = A; slot[1] = B; slot[2] = C; slot[3] = D;   // plain stores, zero contention
    }
}

__device__ inline float ce_for_box0(const float* __restrict__ cp) {
    float c[NC];
#pragma unroll
    for (int j = 0; j < NC; j++) c[j] = cp[j];
    float m = c[0];
#pragma unroll
    for (int j = 1; j < NC; j++) m = fmaxf(m, c[j]);
    float s = 0.f;
#pragma unroll
    for (int j = 0; j < NC; j++) s += __expf(c[j] - m);
    return m + __logf(s) - c[0];
}

// Block r: reduce 35 partial slots -> row sums; mining decision.
// Hot path (K >= #neg, always true on this data): conf_row = row_ce, no sort.
// Cold path: exact top-K radix select (tie values identical -> sum exact).
__global__ void __launch_bounds__(256)
kB(const float* __restrict__ conf, const int* __restrict__ lab,
   float* __restrict__ ws) {
    const int r = blockIdx.x;
    __shared__ float srow[4];
    if (threadIdx.x < 64) {                      // wave 0 reduces the 35 slots
        float a = 0, b = 0, c = 0, d = 0;
        if (threadIdx.x < BX) {
            const float4 p = *(const float4*)(ws + ((size_t)r * BX + threadIdx.x) * 4);
            a = p.x; b = p.y; c = p.z; d = p.w;
        }
        a = wred_f(a); b = wred_f(b); c = wred_f(c); d = wred_f(d);
        if (threadIdx.x == 0) { srow[0] = a; srow[1] = b; srow[2] = c; srow[3] = d; }
    }
    __syncthreads();
    const float row_ce = srow[0], row_pce = srow[1], row_ll = srow[2];
    const int np = (int)srow[3];
    const int K = min(3 * np, NB - 1);
    const int nneg = NB - np;

    float rowval;
    if (K >= nneg) {
        rowval = row_ce;
    } else if (K <= 0) {
        rowval = row_pce;
    } else {
        __shared__ unsigned key[NB];
        __shared__ unsigned hist[256];
        __shared__ unsigned sb[2];
        for (int i = threadIdx.x; i < NB; i += 256) {
            const size_t box = (size_t)r * NB + i;
            unsigned k = 0u;
            if (lab[box] == 0) {
                float ce = ce_for_box0(conf + box * (size_t)NC);
                k = __float_as_uint(fmaxf(ce, 0.f));
            }
            key[i] = k;
        }
        __syncthreads();
        unsigned prefix = 0;
        int Kr = K;
        for (int round = 3; round >= 0; --round) {
            const int sh = round * 8;
            const unsigned pmask = (round == 3) ? 0u : (0xFFFFFFFFu << (8 * (round + 1)));
            for (int b = threadIdx.x; b < 256; b += 256) hist[b] = 0;
            __syncthreads();
            for (int i = threadIdx.x; i < NB; i += 256) {
                const unsigned k = key[i];
                if ((k & pmask) == prefix) atomicAdd(&hist[(k >> sh) & 255u], 1u);
            }
            __syncthreads();
            if (threadIdx.x == 0) {
                unsigned cum = 0; int b = 255;
                for (; b > 0; --b) {
                    const unsigned h = hist[b];
                    if (cum + h >= (unsigned)Kr) break;
                    cum += h;
                }
                sb[0] = cum; sb[1] = (unsigned)b;
            }
            __syncthreads();
            Kr -= (int)sb[0];
            prefix |= (sb[1] << sh);
            __syncthreads();
        }
        float local = 0.f;
        for (int i = threadIdx.x; i < NB; i += 256) {
            const unsigned k = key[i];
            if (k > prefix) local += __uint_as_float(k);
        }
        __shared__ float sred[4];
        float vv = wred_f(local);
        const int ww = threadIdx.x >> 6, lnn = threadIdx.x & 63;
        if (lnn == 0) sred[ww] = vv;
        __syncthreads();
        rowval = row_pce + sred[0] + sred[1] + sred[2] + sred[3]
               + (float)Kr * __uint_as_float(prefix);
    }

    if (threadIdx.x == 0) {
        float* o = ws + WS_ROW + r * 4;
        o[0] = rowval; o[1] = row_ll; o[2] = srow[3];
    }
}

// Single block: reduce the 128 per-row results -> final scalar.
__global__ void __launch_bounds__(256)
kC(const float* __restrict__ ws, float* __restrict__ out) {
    float cf = 0.f, lc = 0.f, nm = 0.f;
    if (threadIdx.x < BATCH) {
        const float* o = ws + WS_ROW + threadIdx.x * 4;
        cf = o[0]; lc = o[1]; nm = o[2];
    }
    __shared__ float sf[4], sl[4], sn[4];
    float vc = wred_f(cf), vl = wred_f(lc), vn = wred_f(nm);
    const int w = threadIdx.x >> 6, ln = threadIdx.x & 63;
    if (ln == 0) { sf[w] = vc; sl[w] = vl; sn[w] = vn; }
    __syncthreads();
    if (threadIdx.x == 0) {
        const float CF = sf[0] + sf[1] + sf[2] + sf[3];
        const float LC = sl[0] + sl[1] + sl[2] + sl[3];
        const float NM = sn[0] + sn[1] + sn[2] + sn[3];
        out[0] = (LC + CF) / fmaxf(NM, 1.f);
    }
}

extern "C" void kernel_launch(void* const* d_in, const int* in_sizes, int n_in,
                              void* d_out, int out_size, void* d_ws, size_t ws_size,
                              hipStream_t stream) {
    const float* locp = (const float*)d_in[0];
    const float* loct = (const float*)d_in[1];
    const float* conf = (const float*)d_in[2];
    const int* lab = (const int*)d_in[3];
    float* out = (float*)d_out;
    float* ws = (float*)d_ws;

    hipLaunchKernelGGL(kA, dim3(BX, BATCH), dim3(256), 0, stream,
                       locp, loct, conf, lab, ws);
    hipLaunchKernelGGL(kB, dim3(BATCH), dim3(256), 0, stream, conf, lab, ws);
    hipLaunchKernelGGL(kC, dim3(1), dim3(256), 0, stream, ws, out);
}